// Round 15
// baseline (470.311 us; speedup 1.0000x reference)
//
#include <hip/hip_runtime.h>
#include <math.h>

#define TT 3
#define LL 3
#define EE 50000
#define NN 1000000
#define RR 200
#define NRELC 401
#define HH 256
#define BB 8
#define KTOP 1000
#define SROW 24            // e-major state stride: s[e*24 + row], row = b*3+l

__device__ __forceinline__ float sigmoidf_(float x) {
    if (x >= 0.f) { return 1.f / (1.f + expf(-x)); }
    float z = expf(x); return z / (1.f + z);
}

// ================= Phase A: LSTM as wave-per-row GEMV pipeline =================
__global__ __launch_bounds__(256) void pre_kernel(
    const int* __restrict__ input_r, const float* __restrict__ emb,
    const float* __restrict__ Wih_f, const float* __restrict__ bih_f, const float* __restrict__ bhh_f,
    const float* __restrict__ Wih_b, const float* __restrict__ bih_b, const float* __restrict__ bhh_b,
    float* __restrict__ preq, float* __restrict__ pree)
{
    int wave = blockIdx.x * 4 + (threadIdx.x >> 6);
    if (wave >= 1536) return;                 // 6144 rows / 4
    int lane = threadIdx.x & 63;
    int row0 = wave * 4;
    int ld = row0 >> 10;                      // 0..5 = l*2+dir
    int l = ld >> 1, dir = ld & 1;
    const float* Wih = (dir ? Wih_b : Wih_f) + (size_t)l * 4 * HH * HH;
    const float* bih = (dir ? bih_b : bih_f) + l * 4 * HH;
    const float* bhh = (dir ? bhh_b : bhh_f) + l * 4 * HH;

    float4 xf[9];
    for (int b = 0; b < 8; ++b) {
        int r = input_r[b];
        xf[b] = *(const float4*)(emb + (size_t)r * HH + lane * 4);
    }
    xf[8] = *(const float4*)(emb + (size_t)(NRELC - 1) * HH + lane * 4);

    for (int rr = 0; rr < 4; ++rr) {
        int row = (row0 + rr) & 1023;
        float4 w4 = *(const float4*)(Wih + (size_t)row * HH + lane * 4);
        float acc[9];
        #pragma unroll
        for (int c = 0; c < 9; ++c)
            acc[c] = w4.x * xf[c].x + w4.y * xf[c].y + w4.z * xf[c].z + w4.w * xf[c].w;
        #pragma unroll
        for (int off = 32; off > 0; off >>= 1)
            #pragma unroll
            for (int c = 0; c < 9; ++c) acc[c] += __shfl_xor(acc[c], off);
        float bsum = bih[row] + bhh[row];
        if (lane < 8) preq[((size_t)ld * 8 + lane) * 1024 + row] = acc[lane] + bsum;
        if (lane == 8) pree[(size_t)ld * 1024 + row] = acc[8] + bsum;
    }
}

__global__ __launch_bounds__(256) void rec_kernel(
    const float* __restrict__ Whh_f, const float* __restrict__ Whh_b,
    const float* __restrict__ preq, const float* __restrict__ pree,
    const float* __restrict__ hstate, float* __restrict__ gates, int step)
{
    int wave = blockIdx.x * 4 + (threadIdx.x >> 6);
    if (wave >= 1536) return;
    int lane = threadIdx.x & 63;
    int row0 = wave * 4;
    int ld = row0 >> 10;                      // 0..5
    int l = ld >> 1, dir = ld & 1;
    const float* Whh = (dir ? Whh_b : Whh_f) + (size_t)l * 4 * HH * HH;
    bool use_e = dir ? (step == 0) : (step == 3);

    float4 hf[8];
    for (int b = 0; b < 8; ++b)
        hf[b] = *(const float4*)(hstate + ((size_t)ld * 8 + b) * HH + lane * 4);

    for (int rr = 0; rr < 4; ++rr) {
        int row = (row0 + rr) & 1023;
        float4 w4 = *(const float4*)(Whh + (size_t)row * HH + lane * 4);
        float acc[8];
        #pragma unroll
        for (int b = 0; b < 8; ++b)
            acc[b] = w4.x * hf[b].x + w4.y * hf[b].y + w4.z * hf[b].z + w4.w * hf[b].w;
        #pragma unroll
        for (int off = 32; off > 0; off >>= 1)
            #pragma unroll
            for (int b = 0; b < 8; ++b) acc[b] += __shfl_xor(acc[b], off);
        if (lane < 8) {
            float pre = use_e ? pree[(size_t)ld * 1024 + row]
                              : preq[((size_t)ld * 8 + lane) * 1024 + row];
            gates[((size_t)ld * 8 + lane) * 1024 + row] = acc[lane] + pre;
        }
    }
}

__global__ __launch_bounds__(256) void hupdate_kernel(
    const float* __restrict__ preq, const float* __restrict__ pree,
    const float* __restrict__ gates, float* __restrict__ hstate,
    float* __restrict__ cstate, float* __restrict__ hbuf2, int step)
{
    int g = blockIdx.x * 256 + threadIdx.x;   // (ld, b, j)
    int ld = g >> 11;                         // 0..5
    int b = (g >> 8) & 7;
    int j = g & 255;
    int dir = ld & 1;
    bool use_e = dir ? (step == 0) : (step == 3);
    float gv[4];
    #pragma unroll
    for (int q = 0; q < 4; ++q) {
        int row = q * 256 + j;
        if (step == 0)
            gv[q] = use_e ? pree[(size_t)ld * 1024 + row]
                          : preq[((size_t)ld * 8 + b) * 1024 + row];
        else
            gv[q] = gates[((size_t)ld * 8 + b) * 1024 + row];
    }
    float c = (step == 0) ? 0.f : cstate[g];
    float iv = sigmoidf_(gv[0]), fv = sigmoidf_(gv[1]);
    float gg = tanhf(gv[2]),     ov = sigmoidf_(gv[3]);
    c = fv * c + iv * gg;
    float h = ov * tanhf(c);
    cstate[g] = c;
    hstate[g] = h;
    int t_out = dir ? (3 - step) : step;
    if (t_out <= 2) hbuf2[(((size_t)ld * 8 + b) * 3 + t_out) * HH + j] = h;
}

__global__ __launch_bounds__(256) void logits_dot(
    const float* __restrict__ hbuf2, const float* __restrict__ linW,
    const float* __restrict__ linb, float* __restrict__ wbuf)
{
    int wave = blockIdx.x * 4 + (threadIdx.x >> 6);
    if (wave >= 3 * 3 * NRELC) return;
    int lane = threadIdx.x & 63;
    int n = wave % NRELC;
    int tc = wave / NRELC;          // 0..8
    int t = tc / 3, chunk = tc % 3;
    const float4* wr = (const float4*)(linW + (size_t)n * 2 * HH + lane * 8);
    float4 w4a = wr[0], w4b = wr[1];
    float acc[8];
    #pragma unroll
    for (int i = 0; i < 8; ++i) {
        int combo = chunk * 8 + i;      // combo = b*3 + l
        int b = combo / 3, l = combo % 3;
        int ldh = (lane < 32) ? (l * 2 + 0) : (l * 2 + 1);
        const float* hsrc = hbuf2 + (((size_t)ldh * 8 + b) * 3 + t) * HH + (lane & 31) * 8;
        float4 f0 = *(const float4*)hsrc;
        float4 f1 = *(const float4*)(hsrc + 4);
        acc[i] = w4a.x * f0.x + w4a.y * f0.y + w4a.z * f0.z + w4a.w * f0.w
               + w4b.x * f1.x + w4b.y * f1.y + w4b.z * f1.z + w4b.w * f1.w;
    }
    #pragma unroll
    for (int off = 32; off > 0; off >>= 1)
        #pragma unroll
        for (int i = 0; i < 8; ++i) acc[i] += __shfl_xor(acc[i], off);
    if (lane < 8) {
        int combo = chunk * 8 + lane;
        wbuf[((size_t)t * 24 + combo) * NRELC + n] = acc[lane] + linb[n];
    }
}

__global__ __launch_bounds__(256) void softmax_kernel(float* __restrict__ wbuf) {
    int rowi = blockIdx.x;                        // t*24 + combo
    float* w = wbuf + (size_t)rowi * NRELC;
    __shared__ float red[256];
    int tid = threadIdx.x;
    float v0 = w[tid];
    float v1 = (tid + 256 < NRELC) ? w[tid + 256] : -1e30f;
    red[tid] = fmaxf(v0, v1); __syncthreads();
    for (int s2 = 128; s2 > 0; s2 >>= 1) {
        if (tid < s2) red[tid] = fmaxf(red[tid], red[tid + s2]);
        __syncthreads();
    }
    float m = red[0]; __syncthreads();
    float e0 = expf((v0 - m) * 0.1f);
    float e1 = (tid + 256 < NRELC) ? expf((v1 - m) * 0.1f) : 0.f;
    red[tid] = e0 + e1; __syncthreads();
    for (int s2 = 128; s2 > 0; s2 >>= 1) {
        if (tid < s2) red[tid] += red[tid + s2];
        __syncthreads();
    }
    float denom = red[0];
    w[tid] = e0 / denom;
    if (tid + 256 < NRELC) w[tid + 256] = e1 / denom;
}

// ================= utility fill =================
__global__ void fill_zero_f(float* __restrict__ p, int n) {
    int i = blockIdx.x * 256 + threadIdx.x;
    if (i < n) p[i] = 0.f;
}

// ================= hop 0: fused zero-fill + one-hot seed (e-major) =================
__global__ __launch_bounds__(256) void fill_seed(
    float* __restrict__ s, const int* __restrict__ input_x, const float* __restrict__ w0)
{
    __shared__ int xs[8];
    __shared__ float wv[24];
    if (threadIdx.x < 8) xs[threadIdx.x] = input_x[threadIdx.x];
    if (threadIdx.x < 24) wv[threadIdx.x] = w0[(size_t)threadIdx.x * NRELC + (NRELC - 1)];
    __syncthreads();
    int i = blockIdx.x * 256 + threadIdx.x;
    if (i >= SROW * EE) return;
    int row = i % 24;
    int e = i / 24;
    s[i] = (e == xs[row / 3]) ? wv[row] : 0.f;
}

__global__ __launch_bounds__(256) void hop0_scan(
    const int* __restrict__ heads, const int* __restrict__ tails,
    const int* __restrict__ tails2, const int* __restrict__ rels,
    const int* __restrict__ input_x, const float* __restrict__ w0,
    float* __restrict__ s)
{
    __shared__ int xs[BB];
    if (threadIdx.x < BB) xs[threadIdx.x] = input_x[threadIdx.x];
    __syncthreads();
    int i = blockIdx.x * 256 + threadIdx.x;
    if (i >= NN) return;
    int h = heads[i], t2 = tails2[i];
    bool any = false;
    #pragma unroll
    for (int b = 0; b < BB; ++b) any = any || (h == xs[b]) || (t2 == xs[b]);
    if (!any) return;
    int tl = tails[i], rr = rels[i];
    for (int b = 0; b < BB; ++b) {
        if (h == xs[b])
            for (int l = 0; l < LL; ++l)
                atomicAdd(&s[(size_t)tl * SROW + b * 3 + l], w0[(b * 3 + l) * NRELC + rr]);
        if (t2 == xs[b])
            for (int l = 0; l < LL; ++l)
                atomicAdd(&s[(size_t)h * SROW + b * 3 + l], w0[(b * 3 + l) * NRELC + rr + RR]);
    }
}

// ================= row sums + nonzero compaction (for topk) =================
__global__ __launch_bounds__(256) void rowsum_compact(
    const float* __restrict__ s, float* __restrict__ partial,
    unsigned* __restrict__ ckey, unsigned char* __restrict__ crow,
    unsigned* __restrict__ ncnt, int do_compact)
{
    __shared__ float acc[24];
    __shared__ unsigned lkey[3584];
    __shared__ unsigned char lrow[3584];
    __shared__ unsigned lcnt, gbase;
    int tid = threadIdx.x;
    if (tid < 24) acc[tid] = 0.f;
    if (tid == 0) lcnt = 0;
    __syncthreads();
    int gidx = blockIdx.x * 256 + tid;
    int row = gidx % 24;
    float a = 0.f;
    const int total = SROW * EE;              // 1,200,000
    for (int k0 = 0; k0 < 52; k0 += 13) {     // 4 chunks x 13 strides
        for (int kk = 0; kk < 13; ++kk) {
            long i = (long)gidx + (long)(k0 + kk) * 24576;
            if (i < total) {
                float v = s[i];
                a += v;
                if (do_compact && __float_as_uint(v) != 0u) {
                    unsigned slot = atomicAdd(&lcnt, 1u);
                    lkey[slot] = __float_as_uint(v);
                    lrow[slot] = (unsigned char)row;
                }
            }
        }
        if (do_compact) {
            __syncthreads();
            if (tid == 0) gbase = atomicAdd(ncnt, lcnt);
            __syncthreads();
            unsigned cnt = lcnt;
            for (unsigned j = tid; j < cnt; j += 256) {
                ckey[gbase + j] = lkey[j];
                crow[gbase + j] = lrow[j];
            }
            __syncthreads();
            if (tid == 0) lcnt = 0;
            __syncthreads();
        }
    }
    atomicAdd(&acc[row], a);
    __syncthreads();
    if (tid < 24) partial[blockIdx.x * 24 + tid] = acc[tid];
}

__global__ __launch_bounds__(256) void rowsum_fin(
    const float* __restrict__ partial, float* __restrict__ sums,
    const float* __restrict__ w_t, float* __restrict__ wsc)
{
    int tid = threadIdx.x;
    __shared__ float ss[24];
    if (tid < 24) {
        float a = 0.f;
        for (int j = 0; j < 96; ++j) a += partial[j * 24 + tid];
        a = fmaxf(a, 1e-7f);
        sums[tid] = a;
        ss[tid] = a;
    }
    __syncthreads();
    if (w_t != nullptr) {
        for (int i = tid; i < 24 * NRELC; i += 256)
            wsc[i] = w_t[i] / ss[i / NRELC];
    }
}

// ================= exact k-th largest: 4-round radix select on COMPACT list ============
__global__ __launch_bounds__(256) void topk_hist_c(
    const unsigned* __restrict__ ckey, const unsigned char* __restrict__ crow,
    const unsigned* __restrict__ ncnt, const unsigned* __restrict__ selp,
    unsigned* __restrict__ ghist, int round)
{
    __shared__ unsigned lh[6144];
    __shared__ unsigned sp[24];
    for (int i = threadIdx.x; i < 6144; i += 256) lh[i] = 0;
    if (threadIdx.x < 24) sp[threadIdx.x] = (round == 0) ? 0u : selp[threadIdx.x];
    __syncthreads();
    int n = (int)*ncnt;
    int shift = 24 - 8 * round;
    for (int i = blockIdx.x * 256 + threadIdx.x; i < n; i += gridDim.x * 256) {
        unsigned key = ckey[i];
        int row = crow[i];
        if (round != 0 && (key >> (shift + 8)) != sp[row]) continue;
        atomicAdd(&lh[row * 256 + ((key >> shift) & 255u)], 1u);
    }
    __syncthreads();
    for (int i = threadIdx.x; i < 6144; i += 256)
        if (lh[i]) atomicAdd(&ghist[i], lh[i]);
}

__global__ __launch_bounds__(256) void topk_pick(
    unsigned* __restrict__ ghist, unsigned* __restrict__ selp,
    int* __restrict__ selk, float* __restrict__ th, int* __restrict__ mask,
    int round)
{
    int row = blockIdx.x, tid = threadIdx.x;
    int cnt = (int)ghist[row * 256 + tid];
    ghist[row * 256 + tid] = 0;                   // re-arm for next round
    __shared__ int red[256];
    red[tid] = cnt; __syncthreads();
    for (int off = 1; off < 256; off <<= 1) {     // inclusive suffix scan
        int v = (tid + off < 256) ? red[tid + off] : 0;
        __syncthreads();
        red[tid] += v;
        __syncthreads();
    }
    int above = (tid == 255) ? 0 : red[tid + 1];
    int remk = (round == 0) ? KTOP : selk[row];
    __shared__ int sh_bin, sh_rem;
    if (tid == 0) { sh_bin = 0; sh_rem = remk; }  // default: k-th lies among zeros
    __syncthreads();
    if (above < remk && above + cnt >= remk) { sh_bin = tid; sh_rem = remk - above; }
    __syncthreads();
    if (tid == 0) {
        unsigned prefix = (round == 0) ? 0u : selp[row];
        unsigned np = (prefix << 8) | (unsigned)sh_bin;
        selp[row] = np; selk[row] = sh_rem;
        if (round == 3) th[row] = __uint_as_float(np);
    }
    if (round == 3) {                             // fold mask zeroing into last pick
        int per = (EE + 23) / 24;
        int e0 = row * per, e1 = min(e0 + per, EE);
        for (int e = e0 + tid; e < e1; e += 256) mask[e] = 0;
    }
}

// ================= prune + identity seed + mask (flat, e-major, unnormalized) ==========
__global__ __launch_bounds__(256) void prune_flat(
    float* __restrict__ s, const float* __restrict__ th,
    const float* __restrict__ wsc, float* __restrict__ x, int* __restrict__ mask,
    unsigned* __restrict__ ncnt)
{
    __shared__ float ths[24], w4s[24];
    if (threadIdx.x < 24) {
        ths[threadIdx.x] = th[threadIdx.x];
        w4s[threadIdx.x] = wsc[threadIdx.x * NRELC + (NRELC - 1)];  // w400/sum
    }
    if (blockIdx.x == 0 && threadIdx.x == 0) *ncnt = 0;  // re-arm compact cursor
    __syncthreads();
    int i = blockIdx.x * 256 + threadIdx.x;
    if (i >= SROW * EE) return;
    int row = i % 24;
    int e = i / 24;
    float v = s[i];
    float xv = (v >= ths[row]) ? v : 0.f;
    x[i] = xv;
    s[i] = w4s[row] * xv;
    if (xv > 0.f) atomicOr(&mask[e], 1 << (row / 3));
}

// ================= hops 1..2: (triple-coalesced, b = blockIdx.y) masked scatter ========
// Consecutive lanes cover consecutive triples -> index loads fully coalesced
// (64 triples per wave-load vs 8 in the gid&7 layout). The 8 b-slices re-read the
// 8 MB index arrays, but they stay L3-resident (256 MB) so HBM FETCH is unchanged.
__global__ __launch_bounds__(256) void hop_scan(
    const int* __restrict__ heads, const int* __restrict__ tails,
    const int* __restrict__ tails2, const int* __restrict__ rels,
    const int* __restrict__ mask, const float* __restrict__ x,
    const float* __restrict__ wsc, float* __restrict__ s)
{
    int i = blockIdx.x * 256 + threadIdx.x;
    if (i >= NN) return;
    int b = blockIdx.y;
    int h = heads[i], t2 = tails2[i];
    int mh = mask[h], mt = mask[t2];
    bool ah = (mh >> b) & 1;
    bool at = (mt >> b) & 1;
    if (!(ah || at)) return;
    int tl = tails[i], rr = rels[i];
    int row = b * 3;
    if (ah) {
        float v0 = x[(size_t)h * SROW + row];
        float v1 = x[(size_t)h * SROW + row + 1];
        float v2 = x[(size_t)h * SROW + row + 2];
        if (v0 != 0.f) atomicAdd(&s[(size_t)tl * SROW + row],     v0 * wsc[(row)     * NRELC + rr]);
        if (v1 != 0.f) atomicAdd(&s[(size_t)tl * SROW + row + 1], v1 * wsc[(row + 1) * NRELC + rr]);
        if (v2 != 0.f) atomicAdd(&s[(size_t)tl * SROW + row + 2], v2 * wsc[(row + 2) * NRELC + rr]);
    }
    if (at) {
        float v0 = x[(size_t)t2 * SROW + row];
        float v1 = x[(size_t)t2 * SROW + row + 1];
        float v2 = x[(size_t)t2 * SROW + row + 2];
        if (v0 != 0.f) atomicAdd(&s[(size_t)h * SROW + row],     v0 * wsc[(row)     * NRELC + rr + RR]);
        if (v1 != 0.f) atomicAdd(&s[(size_t)h * SROW + row + 1], v1 * wsc[(row + 1) * NRELC + rr + RR]);
        if (v2 != 0.f) atomicAdd(&s[(size_t)h * SROW + row + 2], v2 * wsc[(row + 2) * NRELC + rr + RR]);
    }
}

// ================= final (e-major, normalizes on the fly) =================
__global__ void final_kernel(const float* __restrict__ s, const float* __restrict__ sums,
                             float* __restrict__ out) {
    __shared__ float ss[24];
    if (threadIdx.x < 24) ss[threadIdx.x] = sums[threadIdx.x];
    __syncthreads();
    int e = blockIdx.x * 256 + threadIdx.x;
    if (e >= EE) return;
    const float* se = s + (size_t)e * SROW;
    #pragma unroll
    for (int b = 0; b < 8; ++b)
        out[(size_t)b * EE + e] = se[b * 3] / ss[b * 3]
                                + se[b * 3 + 1] / ss[b * 3 + 1]
                                + se[b * 3 + 2] / ss[b * 3 + 2];
}

extern "C" void kernel_launch(void* const* d_in, const int* in_sizes, int n_in,
                              void* d_out, int out_size, void* d_ws, size_t ws_size,
                              hipStream_t stream)
{
    const int*   input_x  = (const int*)d_in[0];
    const int*   input_r  = (const int*)d_in[1];
    const int*   e2triple = (const int*)d_in[2];
    const int*   triple2e = (const int*)d_in[3];
    const int*   r2triple = (const int*)d_in[4];
    const float* emb      = (const float*)d_in[5];
    const float* Wih_f    = (const float*)d_in[6];
    const float* Whh_f    = (const float*)d_in[7];
    const float* bih_f    = (const float*)d_in[8];
    const float* bhh_f    = (const float*)d_in[9];
    const float* Wih_b    = (const float*)d_in[10];
    const float* Whh_b    = (const float*)d_in[11];
    const float* bih_b    = (const float*)d_in[12];
    const float* bhh_b    = (const float*)d_in[13];
    const float* linW     = (const float*)d_in[14];
    const float* linb     = (const float*)d_in[15];

    const int* heads  = e2triple;
    const int* tails2 = e2triple + 2 * (size_t)NN;
    const int* tails  = triple2e + (size_t)NN;
    const int* rels   = r2triple;

    // workspace layout (~16.1 MB; ws >= 18.7 MB proven by round 10's CSR build)
    float* ws      = (float*)d_ws;
    float* hbuf    = ws;                          // 36864
    float* wbuf    = hbuf + 36864;                // 28872
    float* xst     = wbuf + 28872;                // 1200000 (e-major [E][24])
    float* sst     = xst + 1200000;               // 1200000
    float* sums    = sst + 1200000;               // 24
    float* th      = sums + 24;                   // 24
    int*   mask    = (int*)(th + 24);             // 50000
    float* partial = (float*)(mask + EE);         // 2304
    unsigned* ghist = (unsigned*)(partial + 2304);// 6144 (shared hist)
    unsigned* selp  = ghist + 6144;               // 24
    int*      selk  = (int*)(selp + 24);          // 24
    unsigned* ncnt  = (unsigned*)(selk + 24);     // 8 (cursor + pad)
    unsigned* ckey  = ncnt + 8;                   // 1200000 u32 (compact keys)
    unsigned char* crow = (unsigned char*)(ckey + SROW * EE);  // 1200000 u8
    // aliases
    float* wsc    = hbuf;                         // 9624, dead after logits_dot
    float* preq   = xst;                          // phase-A scratch (dead before prune t=1)
    float* pree   = preq + 49152;
    float* gates  = pree + 6144;
    float* hstate = gates + 49152;
    float* cstate = hstate + 12288;

    float* out = (float*)d_out;
    const int EBLK  = (EE + 255) / 256;           // 196
    const int SBLK  = (SROW * EE + 255) / 256;    // 4688
    const int NBLK  = (NN + 255) / 256;           // 3907

    // ---- Phase A ----
    pre_kernel<<<384, 256, 0, stream>>>(input_r, emb, Wih_f, bih_f, bhh_f,
                                        Wih_b, bih_b, bhh_b, preq, pree);
    hupdate_kernel<<<48, 256, 0, stream>>>(preq, pree, gates, hstate, cstate, hbuf, 0);
    for (int s = 1; s <= 3; ++s) {
        rec_kernel<<<384, 256, 0, stream>>>(Whh_f, Whh_b, preq, pree, hstate, gates, s);
        hupdate_kernel<<<48, 256, 0, stream>>>(preq, pree, gates, hstate, cstate, hbuf, s);
    }
    logits_dot<<<903, 256, 0, stream>>>(hbuf, linW, linb, wbuf);
    softmax_kernel<<<72, 256, 0, stream>>>(wbuf);

    // arm shared hist + selp/selk + compact cursor (ws is poisoned every call)
    fill_zero_f<<<25, 256, 0, stream>>>((float*)ghist, 6144 + 24 + 24 + 8);

    // ---- hop 0 (fused fill+seed, scatter over tiny active set) into sst ----
    fill_seed<<<SBLK, 256, 0, stream>>>(sst, input_x, wbuf);
    hop0_scan<<<NBLK, 256, 0, stream>>>(heads, tails, tails2, rels, input_x, wbuf, sst);
    rowsum_compact<<<96, 256, 0, stream>>>(sst, partial, ckey, crow, ncnt, 1);
    rowsum_fin<<<1, 256, 0, stream>>>(partial, sums, wbuf + 1 * 24 * NRELC, wsc);

    // ---- hops 1,2 (unnormalized state; weights carry 1/sum) ----
    for (int t = 1; t < TT; ++t) {
        for (int r = 0; r < 4; ++r) {
            topk_hist_c<<<64, 256, 0, stream>>>(ckey, crow, ncnt, selp, ghist, r);
            topk_pick<<<24, 256, 0, stream>>>(ghist, selp, selk, th, mask, r);
        }
        prune_flat<<<SBLK, 256, 0, stream>>>(sst, th, wsc, xst, mask, ncnt);
        hop_scan<<<dim3(NBLK, 8), 256, 0, stream>>>(heads, tails, tails2, rels, mask, xst, wsc, sst);
        rowsum_compact<<<96, 256, 0, stream>>>(sst, partial, ckey, crow, ncnt,
                                               (t + 1 < TT) ? 1 : 0);
        const float* w_next = (t + 1 < TT) ? (wbuf + (size_t)(t + 1) * 24 * NRELC) : nullptr;
        rowsum_fin<<<1, 256, 0, stream>>>(partial, sums, w_next, wsc);
    }

    final_kernel<<<EBLK, 256, 0, stream>>>(sst, sums, out);
}

// Round 16
// 391.537 us; speedup vs baseline: 1.2012x; 1.2012x over previous
//
#include <hip/hip_runtime.h>
#include <math.h>

#define TT 3
#define LL 3
#define EE 50000
#define NN 1000000
#define RR 200
#define NRELC 401
#define HH 256
#define BB 8
#define KTOP 1000
#define SROW 24            // e-major state stride: s[e*24 + row], row = b*3+l

__device__ __forceinline__ float sigmoidf_(float x) {
    if (x >= 0.f) { return 1.f / (1.f + expf(-x)); }
    float z = expf(x); return z / (1.f + z);
}

// ================= Phase A: LSTM as wave-per-row GEMV pipeline =================
__global__ __launch_bounds__(256) void pre_kernel(
    const int* __restrict__ input_r, const float* __restrict__ emb,
    const float* __restrict__ Wih_f, const float* __restrict__ bih_f, const float* __restrict__ bhh_f,
    const float* __restrict__ Wih_b, const float* __restrict__ bih_b, const float* __restrict__ bhh_b,
    float* __restrict__ preq, float* __restrict__ pree)
{
    int wave = blockIdx.x * 4 + (threadIdx.x >> 6);
    if (wave >= 1536) return;                 // 6144 rows / 4
    int lane = threadIdx.x & 63;
    int row0 = wave * 4;
    int ld = row0 >> 10;                      // 0..5 = l*2+dir
    int l = ld >> 1, dir = ld & 1;
    const float* Wih = (dir ? Wih_b : Wih_f) + (size_t)l * 4 * HH * HH;
    const float* bih = (dir ? bih_b : bih_f) + l * 4 * HH;
    const float* bhh = (dir ? bhh_b : bhh_f) + l * 4 * HH;

    float4 xf[9];
    for (int b = 0; b < 8; ++b) {
        int r = input_r[b];
        xf[b] = *(const float4*)(emb + (size_t)r * HH + lane * 4);
    }
    xf[8] = *(const float4*)(emb + (size_t)(NRELC - 1) * HH + lane * 4);

    for (int rr = 0; rr < 4; ++rr) {
        int row = (row0 + rr) & 1023;
        float4 w4 = *(const float4*)(Wih + (size_t)row * HH + lane * 4);
        float acc[9];
        #pragma unroll
        for (int c = 0; c < 9; ++c)
            acc[c] = w4.x * xf[c].x + w4.y * xf[c].y + w4.z * xf[c].z + w4.w * xf[c].w;
        #pragma unroll
        for (int off = 32; off > 0; off >>= 1)
            #pragma unroll
            for (int c = 0; c < 9; ++c) acc[c] += __shfl_xor(acc[c], off);
        float bsum = bih[row] + bhh[row];
        if (lane < 8) preq[((size_t)ld * 8 + lane) * 1024 + row] = acc[lane] + bsum;
        if (lane == 8) pree[(size_t)ld * 1024 + row] = acc[8] + bsum;
    }
}

__global__ __launch_bounds__(256) void rec_kernel(
    const float* __restrict__ Whh_f, const float* __restrict__ Whh_b,
    const float* __restrict__ preq, const float* __restrict__ pree,
    const float* __restrict__ hstate, float* __restrict__ gates, int step)
{
    int wave = blockIdx.x * 4 + (threadIdx.x >> 6);
    if (wave >= 1536) return;
    int lane = threadIdx.x & 63;
    int row0 = wave * 4;
    int ld = row0 >> 10;                      // 0..5
    int l = ld >> 1, dir = ld & 1;
    const float* Whh = (dir ? Whh_b : Whh_f) + (size_t)l * 4 * HH * HH;
    bool use_e = dir ? (step == 0) : (step == 3);

    float4 hf[8];
    for (int b = 0; b < 8; ++b)
        hf[b] = *(const float4*)(hstate + ((size_t)ld * 8 + b) * HH + lane * 4);

    for (int rr = 0; rr < 4; ++rr) {
        int row = (row0 + rr) & 1023;
        float4 w4 = *(const float4*)(Whh + (size_t)row * HH + lane * 4);
        float acc[8];
        #pragma unroll
        for (int b = 0; b < 8; ++b)
            acc[b] = w4.x * hf[b].x + w4.y * hf[b].y + w4.z * hf[b].z + w4.w * hf[b].w;
        #pragma unroll
        for (int off = 32; off > 0; off >>= 1)
            #pragma unroll
            for (int b = 0; b < 8; ++b) acc[b] += __shfl_xor(acc[b], off);
        if (lane < 8) {
            float pre = use_e ? pree[(size_t)ld * 1024 + row]
                              : preq[((size_t)ld * 8 + lane) * 1024 + row];
            gates[((size_t)ld * 8 + lane) * 1024 + row] = acc[lane] + pre;
        }
    }
}

__global__ __launch_bounds__(256) void hupdate_kernel(
    const float* __restrict__ preq, const float* __restrict__ pree,
    const float* __restrict__ gates, float* __restrict__ hstate,
    float* __restrict__ cstate, float* __restrict__ hbuf2, int step)
{
    int g = blockIdx.x * 256 + threadIdx.x;   // (ld, b, j)
    int ld = g >> 11;                         // 0..5
    int b = (g >> 8) & 7;
    int j = g & 255;
    int dir = ld & 1;
    bool use_e = dir ? (step == 0) : (step == 3);
    float gv[4];
    #pragma unroll
    for (int q = 0; q < 4; ++q) {
        int row = q * 256 + j;
        if (step == 0)
            gv[q] = use_e ? pree[(size_t)ld * 1024 + row]
                          : preq[((size_t)ld * 8 + b) * 1024 + row];
        else
            gv[q] = gates[((size_t)ld * 8 + b) * 1024 + row];
    }
    float c = (step == 0) ? 0.f : cstate[g];
    float iv = sigmoidf_(gv[0]), fv = sigmoidf_(gv[1]);
    float gg = tanhf(gv[2]),     ov = sigmoidf_(gv[3]);
    c = fv * c + iv * gg;
    float h = ov * tanhf(c);
    cstate[g] = c;
    hstate[g] = h;
    int t_out = dir ? (3 - step) : step;
    if (t_out <= 2) hbuf2[(((size_t)ld * 8 + b) * 3 + t_out) * HH + j] = h;
}

__global__ __launch_bounds__(256) void logits_dot(
    const float* __restrict__ hbuf2, const float* __restrict__ linW,
    const float* __restrict__ linb, float* __restrict__ wbuf)
{
    int wave = blockIdx.x * 4 + (threadIdx.x >> 6);
    if (wave >= 3 * 3 * NRELC) return;
    int lane = threadIdx.x & 63;
    int n = wave % NRELC;
    int tc = wave / NRELC;          // 0..8
    int t = tc / 3, chunk = tc % 3;
    const float4* wr = (const float4*)(linW + (size_t)n * 2 * HH + lane * 8);
    float4 w4a = wr[0], w4b = wr[1];
    float acc[8];
    #pragma unroll
    for (int i = 0; i < 8; ++i) {
        int combo = chunk * 8 + i;      // combo = b*3 + l
        int b = combo / 3, l = combo % 3;
        int ldh = (lane < 32) ? (l * 2 + 0) : (l * 2 + 1);
        const float* hsrc = hbuf2 + (((size_t)ldh * 8 + b) * 3 + t) * HH + (lane & 31) * 8;
        float4 f0 = *(const float4*)hsrc;
        float4 f1 = *(const float4*)(hsrc + 4);
        acc[i] = w4a.x * f0.x + w4a.y * f0.y + w4a.z * f0.z + w4a.w * f0.w
               + w4b.x * f1.x + w4b.y * f1.y + w4b.z * f1.z + w4b.w * f1.w;
    }
    #pragma unroll
    for (int off = 32; off > 0; off >>= 1)
        #pragma unroll
        for (int i = 0; i < 8; ++i) acc[i] += __shfl_xor(acc[i], off);
    if (lane < 8) {
        int combo = chunk * 8 + lane;
        wbuf[((size_t)t * 24 + combo) * NRELC + n] = acc[lane] + linb[n];
    }
}

__global__ __launch_bounds__(256) void softmax_kernel(float* __restrict__ wbuf) {
    int rowi = blockIdx.x;                        // t*24 + combo
    float* w = wbuf + (size_t)rowi * NRELC;
    __shared__ float red[256];
    int tid = threadIdx.x;
    float v0 = w[tid];
    float v1 = (tid + 256 < NRELC) ? w[tid + 256] : -1e30f;
    red[tid] = fmaxf(v0, v1); __syncthreads();
    for (int s2 = 128; s2 > 0; s2 >>= 1) {
        if (tid < s2) red[tid] = fmaxf(red[tid], red[tid + s2]);
        __syncthreads();
    }
    float m = red[0]; __syncthreads();
    float e0 = expf((v0 - m) * 0.1f);
    float e1 = (tid + 256 < NRELC) ? expf((v1 - m) * 0.1f) : 0.f;
    red[tid] = e0 + e1; __syncthreads();
    for (int s2 = 128; s2 > 0; s2 >>= 1) {
        if (tid < s2) red[tid] += red[tid + s2];
        __syncthreads();
    }
    float denom = red[0];
    w[tid] = e0 / denom;
    if (tid + 256 < NRELC) w[tid + 256] = e1 / denom;
}

// ================= utility fill =================
__global__ void fill_zero_f(float* __restrict__ p, int n) {
    int i = blockIdx.x * 256 + threadIdx.x;
    if (i < n) p[i] = 0.f;
}

// ================= hop 0: fused zero-fill + one-hot seed (e-major) =================
__global__ __launch_bounds__(256) void fill_seed(
    float* __restrict__ s, const int* __restrict__ input_x, const float* __restrict__ w0)
{
    __shared__ int xs[8];
    __shared__ float wv[24];
    if (threadIdx.x < 8) xs[threadIdx.x] = input_x[threadIdx.x];
    if (threadIdx.x < 24) wv[threadIdx.x] = w0[(size_t)threadIdx.x * NRELC + (NRELC - 1)];
    __syncthreads();
    int i = blockIdx.x * 256 + threadIdx.x;
    if (i >= SROW * EE) return;
    int row = i % 24;
    int e = i / 24;
    s[i] = (e == xs[row / 3]) ? wv[row] : 0.f;
}

__global__ __launch_bounds__(256) void hop0_scan(
    const int* __restrict__ heads, const int* __restrict__ tails,
    const int* __restrict__ tails2, const int* __restrict__ rels,
    const int* __restrict__ input_x, const float* __restrict__ w0,
    float* __restrict__ s)
{
    __shared__ int xs[BB];
    if (threadIdx.x < BB) xs[threadIdx.x] = input_x[threadIdx.x];
    __syncthreads();
    int i = blockIdx.x * 256 + threadIdx.x;
    if (i >= NN) return;
    int h = heads[i], t2 = tails2[i];
    bool any = false;
    #pragma unroll
    for (int b = 0; b < BB; ++b) any = any || (h == xs[b]) || (t2 == xs[b]);
    if (!any) return;
    int tl = tails[i], rr = rels[i];
    for (int b = 0; b < BB; ++b) {
        if (h == xs[b])
            for (int l = 0; l < LL; ++l)
                atomicAdd(&s[(size_t)tl * SROW + b * 3 + l], w0[(b * 3 + l) * NRELC + rr]);
        if (t2 == xs[b])
            for (int l = 0; l < LL; ++l)
                atomicAdd(&s[(size_t)h * SROW + b * 3 + l], w0[(b * 3 + l) * NRELC + rr + RR]);
    }
}

// ================= row sums + nonzero compaction (for topk) =================
__global__ __launch_bounds__(256) void rowsum_compact(
    const float* __restrict__ s, float* __restrict__ partial,
    unsigned* __restrict__ ckey, unsigned char* __restrict__ crow,
    unsigned* __restrict__ ncnt, int do_compact)
{
    __shared__ float acc[24];
    __shared__ unsigned lkey[3584];
    __shared__ unsigned char lrow[3584];
    __shared__ unsigned lcnt, gbase;
    int tid = threadIdx.x;
    if (tid < 24) acc[tid] = 0.f;
    if (tid == 0) lcnt = 0;
    __syncthreads();
    int gidx = blockIdx.x * 256 + tid;
    int row = gidx % 24;
    float a = 0.f;
    const int total = SROW * EE;              // 1,200,000
    for (int k0 = 0; k0 < 52; k0 += 13) {     // 4 chunks x 13 strides
        for (int kk = 0; kk < 13; ++kk) {
            long i = (long)gidx + (long)(k0 + kk) * 24576;
            if (i < total) {
                float v = s[i];
                a += v;
                if (do_compact && __float_as_uint(v) != 0u) {
                    unsigned slot = atomicAdd(&lcnt, 1u);
                    lkey[slot] = __float_as_uint(v);
                    lrow[slot] = (unsigned char)row;
                }
            }
        }
        if (do_compact) {
            __syncthreads();
            if (tid == 0) gbase = atomicAdd(ncnt, lcnt);
            __syncthreads();
            unsigned cnt = lcnt;
            for (unsigned j = tid; j < cnt; j += 256) {
                ckey[gbase + j] = lkey[j];
                crow[gbase + j] = lrow[j];
            }
            __syncthreads();
            if (tid == 0) lcnt = 0;
            __syncthreads();
        }
    }
    atomicAdd(&acc[row], a);
    __syncthreads();
    if (tid < 24) partial[blockIdx.x * 24 + tid] = acc[tid];
}

__global__ __launch_bounds__(256) void rowsum_fin(
    const float* __restrict__ partial, float* __restrict__ sums,
    const float* __restrict__ w_t, float* __restrict__ wsc)
{
    int tid = threadIdx.x;
    __shared__ float ss[24];
    if (tid < 24) {
        float a = 0.f;
        for (int j = 0; j < 96; ++j) a += partial[j * 24 + tid];
        a = fmaxf(a, 1e-7f);
        sums[tid] = a;
        ss[tid] = a;
    }
    __syncthreads();
    if (w_t != nullptr) {
        for (int i = tid; i < 24 * NRELC; i += 256)
            wsc[i] = w_t[i] / ss[i / NRELC];
    }
}

// ================= exact k-th largest: 4-round radix select on COMPACT list ============
__global__ __launch_bounds__(256) void topk_hist_c(
    const unsigned* __restrict__ ckey, const unsigned char* __restrict__ crow,
    const unsigned* __restrict__ ncnt, const unsigned* __restrict__ selp,
    unsigned* __restrict__ ghist, int round)
{
    __shared__ unsigned lh[6144];
    __shared__ unsigned sp[24];
    for (int i = threadIdx.x; i < 6144; i += 256) lh[i] = 0;
    if (threadIdx.x < 24) sp[threadIdx.x] = (round == 0) ? 0u : selp[threadIdx.x];
    __syncthreads();
    int n = (int)*ncnt;
    int shift = 24 - 8 * round;
    for (int i = blockIdx.x * 256 + threadIdx.x; i < n; i += gridDim.x * 256) {
        unsigned key = ckey[i];
        int row = crow[i];
        if (round != 0 && (key >> (shift + 8)) != sp[row]) continue;
        atomicAdd(&lh[row * 256 + ((key >> shift) & 255u)], 1u);
    }
    __syncthreads();
    for (int i = threadIdx.x; i < 6144; i += 256)
        if (lh[i]) atomicAdd(&ghist[i], lh[i]);
}

__global__ __launch_bounds__(256) void topk_pick(
    unsigned* __restrict__ ghist, unsigned* __restrict__ selp,
    int* __restrict__ selk, float* __restrict__ th, int* __restrict__ mask,
    int round)
{
    int row = blockIdx.x, tid = threadIdx.x;
    int cnt = (int)ghist[row * 256 + tid];
    ghist[row * 256 + tid] = 0;                   // re-arm for next round
    __shared__ int red[256];
    red[tid] = cnt; __syncthreads();
    for (int off = 1; off < 256; off <<= 1) {     // inclusive suffix scan
        int v = (tid + off < 256) ? red[tid + off] : 0;
        __syncthreads();
        red[tid] += v;
        __syncthreads();
    }
    int above = (tid == 255) ? 0 : red[tid + 1];
    int remk = (round == 0) ? KTOP : selk[row];
    __shared__ int sh_bin, sh_rem;
    if (tid == 0) { sh_bin = 0; sh_rem = remk; }  // default: k-th lies among zeros
    __syncthreads();
    if (above < remk && above + cnt >= remk) { sh_bin = tid; sh_rem = remk - above; }
    __syncthreads();
    if (tid == 0) {
        unsigned prefix = (round == 0) ? 0u : selp[row];
        unsigned np = (prefix << 8) | (unsigned)sh_bin;
        selp[row] = np; selk[row] = sh_rem;
        if (round == 3) th[row] = __uint_as_float(np);
    }
    if (round == 3) {                             // fold mask zeroing into last pick
        int per = (EE + 23) / 24;
        int e0 = row * per, e1 = min(e0 + per, EE);
        for (int e = e0 + tid; e < e1; e += 256) mask[e] = 0;
    }
}

// ================= prune + identity seed + mask (flat, e-major, unnormalized) ==========
__global__ __launch_bounds__(256) void prune_flat(
    float* __restrict__ s, const float* __restrict__ th,
    const float* __restrict__ wsc, float* __restrict__ x, int* __restrict__ mask,
    unsigned* __restrict__ ncnt)
{
    __shared__ float ths[24], w4s[24];
    if (threadIdx.x < 24) {
        ths[threadIdx.x] = th[threadIdx.x];
        w4s[threadIdx.x] = wsc[threadIdx.x * NRELC + (NRELC - 1)];  // w400/sum
    }
    if (blockIdx.x == 0 && threadIdx.x == 0) *ncnt = 0;  // re-arm compact cursor
    __syncthreads();
    int i = blockIdx.x * 256 + threadIdx.x;
    if (i >= SROW * EE) return;
    int row = i % 24;
    int e = i / 24;
    float v = s[i];
    float xv = (v >= ths[row]) ? v : 0.f;
    x[i] = xv;
    s[i] = w4s[row] * xv;
    if (xv > 0.f) atomicOr(&mask[e], 1 << (row / 3));
}

// ================= hops 1..2: (triple, b)-parallel masked scatter (at roofline) ========
// i = gid>>3, b = gid&7: the 8 same-address index loads per triple-group are merged
// by the coalescer (FETCH=13.7MB = minimal). b=blockIdx.y split regressed (59MB fetch).
__global__ __launch_bounds__(256) void hop_scan(
    const int* __restrict__ heads, const int* __restrict__ tails,
    const int* __restrict__ tails2, const int* __restrict__ rels,
    const int* __restrict__ mask, const float* __restrict__ x,
    const float* __restrict__ wsc, float* __restrict__ s)
{
    int gid = blockIdx.x * 256 + threadIdx.x;
    int i = gid >> 3;
    if (i >= NN) return;
    int b = gid & 7;
    int h = heads[i], t2 = tails2[i];
    int mh = mask[h], mt = mask[t2];
    bool ah = (mh >> b) & 1;
    bool at = (mt >> b) & 1;
    if (!(ah || at)) return;
    int tl = tails[i], rr = rels[i];
    int row = b * 3;
    if (ah) {
        float v0 = x[(size_t)h * SROW + row];
        float v1 = x[(size_t)h * SROW + row + 1];
        float v2 = x[(size_t)h * SROW + row + 2];
        if (v0 != 0.f) atomicAdd(&s[(size_t)tl * SROW + row],     v0 * wsc[(row)     * NRELC + rr]);
        if (v1 != 0.f) atomicAdd(&s[(size_t)tl * SROW + row + 1], v1 * wsc[(row + 1) * NRELC + rr]);
        if (v2 != 0.f) atomicAdd(&s[(size_t)tl * SROW + row + 2], v2 * wsc[(row + 2) * NRELC + rr]);
    }
    if (at) {
        float v0 = x[(size_t)t2 * SROW + row];
        float v1 = x[(size_t)t2 * SROW + row + 1];
        float v2 = x[(size_t)t2 * SROW + row + 2];
        if (v0 != 0.f) atomicAdd(&s[(size_t)h * SROW + row],     v0 * wsc[(row)     * NRELC + rr + RR]);
        if (v1 != 0.f) atomicAdd(&s[(size_t)h * SROW + row + 1], v1 * wsc[(row + 1) * NRELC + rr + RR]);
        if (v2 != 0.f) atomicAdd(&s[(size_t)h * SROW + row + 2], v2 * wsc[(row + 2) * NRELC + rr + RR]);
    }
}

// ================= final (e-major, normalizes on the fly) =================
__global__ void final_kernel(const float* __restrict__ s, const float* __restrict__ sums,
                             float* __restrict__ out) {
    __shared__ float ss[24];
    if (threadIdx.x < 24) ss[threadIdx.x] = sums[threadIdx.x];
    __syncthreads();
    int e = blockIdx.x * 256 + threadIdx.x;
    if (e >= EE) return;
    const float* se = s + (size_t)e * SROW;
    #pragma unroll
    for (int b = 0; b < 8; ++b)
        out[(size_t)b * EE + e] = se[b * 3] / ss[b * 3]
                                + se[b * 3 + 1] / ss[b * 3 + 1]
                                + se[b * 3 + 2] / ss[b * 3 + 2];
}

extern "C" void kernel_launch(void* const* d_in, const int* in_sizes, int n_in,
                              void* d_out, int out_size, void* d_ws, size_t ws_size,
                              hipStream_t stream)
{
    const int*   input_x  = (const int*)d_in[0];
    const int*   input_r  = (const int*)d_in[1];
    const int*   e2triple = (const int*)d_in[2];
    const int*   triple2e = (const int*)d_in[3];
    const int*   r2triple = (const int*)d_in[4];
    const float* emb      = (const float*)d_in[5];
    const float* Wih_f    = (const float*)d_in[6];
    const float* Whh_f    = (const float*)d_in[7];
    const float* bih_f    = (const float*)d_in[8];
    const float* bhh_f    = (const float*)d_in[9];
    const float* Wih_b    = (const float*)d_in[10];
    const float* Whh_b    = (const float*)d_in[11];
    const float* bih_b    = (const float*)d_in[12];
    const float* bhh_b    = (const float*)d_in[13];
    const float* linW     = (const float*)d_in[14];
    const float* linb     = (const float*)d_in[15];

    const int* heads  = e2triple;
    const int* tails2 = e2triple + 2 * (size_t)NN;
    const int* tails  = triple2e + (size_t)NN;
    const int* rels   = r2triple;

    // workspace layout (~16.1 MB; ws >= 18.7 MB proven by round 10's CSR build)
    float* ws      = (float*)d_ws;
    float* hbuf    = ws;                          // 36864
    float* wbuf    = hbuf + 36864;                // 28872
    float* xst     = wbuf + 28872;                // 1200000 (e-major [E][24])
    float* sst     = xst + 1200000;               // 1200000
    float* sums    = sst + 1200000;               // 24
    float* th      = sums + 24;                   // 24
    int*   mask    = (int*)(th + 24);             // 50000
    float* partial = (float*)(mask + EE);         // 2304
    unsigned* ghist = (unsigned*)(partial + 2304);// 6144 (shared hist)
    unsigned* selp  = ghist + 6144;               // 24
    int*      selk  = (int*)(selp + 24);          // 24
    unsigned* ncnt  = (unsigned*)(selk + 24);     // 8 (cursor + pad)
    unsigned* ckey  = ncnt + 8;                   // 1200000 u32 (compact keys)
    unsigned char* crow = (unsigned char*)(ckey + SROW * EE);  // 1200000 u8
    // aliases
    float* wsc    = hbuf;                         // 9624, dead after logits_dot
    float* preq   = xst;                          // phase-A scratch (dead before prune t=1)
    float* pree   = preq + 49152;
    float* gates  = pree + 6144;
    float* hstate = gates + 49152;
    float* cstate = hstate + 12288;

    float* out = (float*)d_out;
    const int EBLK  = (EE + 255) / 256;           // 196
    const int SBLK  = (SROW * EE + 255) / 256;    // 4688
    const int NBLK  = (NN + 255) / 256;           // 3907
    const int N8BLK = (NN * 8) / 256;             // 31250

    // ---- Phase A ----
    pre_kernel<<<384, 256, 0, stream>>>(input_r, emb, Wih_f, bih_f, bhh_f,
                                        Wih_b, bih_b, bhh_b, preq, pree);
    hupdate_kernel<<<48, 256, 0, stream>>>(preq, pree, gates, hstate, cstate, hbuf, 0);
    for (int s = 1; s <= 3; ++s) {
        rec_kernel<<<384, 256, 0, stream>>>(Whh_f, Whh_b, preq, pree, hstate, gates, s);
        hupdate_kernel<<<48, 256, 0, stream>>>(preq, pree, gates, hstate, cstate, hbuf, s);
    }
    logits_dot<<<903, 256, 0, stream>>>(hbuf, linW, linb, wbuf);
    softmax_kernel<<<72, 256, 0, stream>>>(wbuf);

    // arm shared hist + selp/selk + compact cursor (ws is poisoned every call)
    fill_zero_f<<<25, 256, 0, stream>>>((float*)ghist, 6144 + 24 + 24 + 8);

    // ---- hop 0 (fused fill+seed, scatter over tiny active set) into sst ----
    fill_seed<<<SBLK, 256, 0, stream>>>(sst, input_x, wbuf);
    hop0_scan<<<NBLK, 256, 0, stream>>>(heads, tails, tails2, rels, input_x, wbuf, sst);
    rowsum_compact<<<96, 256, 0, stream>>>(sst, partial, ckey, crow, ncnt, 1);
    rowsum_fin<<<1, 256, 0, stream>>>(partial, sums, wbuf + 1 * 24 * NRELC, wsc);

    // ---- hops 1,2 (unnormalized state; weights carry 1/sum) ----
    for (int t = 1; t < TT; ++t) {
        for (int r = 0; r < 4; ++r) {
            topk_hist_c<<<64, 256, 0, stream>>>(ckey, crow, ncnt, selp, ghist, r);
            topk_pick<<<24, 256, 0, stream>>>(ghist, selp, selk, th, mask, r);
        }
        prune_flat<<<SBLK, 256, 0, stream>>>(sst, th, wsc, xst, mask, ncnt);
        hop_scan<<<N8BLK, 256, 0, stream>>>(heads, tails, tails2, rels, mask, xst, wsc, sst);
        rowsum_compact<<<96, 256, 0, stream>>>(sst, partial, ckey, crow, ncnt,
                                               (t + 1 < TT) ? 1 : 0);
        const float* w_next = (t + 1 < TT) ? (wbuf + (size_t)(t + 1) * 24 * NRELC) : nullptr;
        rowsum_fin<<<1, 256, 0, stream>>>(partial, sums, w_next, wsc);
    }

    final_kernel<<<EBLK, 256, 0, stream>>>(sst, sums, out);
}